// Round 1
// baseline (509.661 us; speedup 1.0000x reference)
//
#include <hip/hip_runtime.h>
#include <hip/hip_fp16.h>
#include <cstdint>
#include <cstddef>

#define HID 2560
#define NH  32
#define DHD 80
#define DHP 96
#define NB  2
#define NS  2048
#define NL  512

typedef _Float16 half8_t __attribute__((ext_vector_type(8)));
typedef float f32x4_t __attribute__((ext_vector_type(4)));

__device__ __forceinline__ void gload_lds16(const __half* g, __half* l) {
  __builtin_amdgcn_global_load_lds(
      (const __attribute__((address_space(1))) unsigned int*)g,
      (__attribute__((address_space(3))) unsigned int*)l, 16, 0, 0);
}

// ---------------- cast fp32 -> fp16, vectorized x4 ----------------
__global__ __launch_bounds__(256) void cast_f2h(const float* __restrict__ in,
                                                __half* __restrict__ out, int n4) {
  int i = blockIdx.x * 256 + threadIdx.x;
  if (i >= n4) return;
  float4 v = ((const float4*)in)[i];
  union { __half h[4]; uint2 u; } r;
  r.h[0] = __float2half(v.x);
  r.h[1] = __float2half(v.y);
  r.h[2] = __float2half(v.z);
  r.h[3] = __float2half(v.w);
  ((uint2*)out)[i] = r.u;
}

// ---------------- GEMM: C = A[M,K] x Bt[N,K]^T, fp16 in, fp32 acc --------
// 128x128 tile, BK=32, 256 threads (4 waves, 2x2), m97-style structure.
// MODE 0: write Q -> [B,H,S,DHP] fp16, folded softmax scale
// MODE 1: write K -> [B,H,L,DHP] fp16
// MODE 2: write V -> [B,H,DHP,L] fp16 (transposed for PV B^T-pattern)
// MODE 3: write out = gate * acc, fp32 [M,HID]
template<int MODE>
__global__ __launch_bounds__(256) void gemm_bt(const __half* __restrict__ A,
                                               const __half* __restrict__ Bt,
                                               void* __restrict__ Cout,
                                               int M, int N, int K,
                                               const float* __restrict__ gate_p) {
  __shared__ __half As[128 * 32];
  __shared__ __half Bs[128 * 32];
  const int tid  = threadIdx.x;
  const int lane = tid & 63;
  const int wave = tid >> 6;
  const int wr = wave >> 1, wc = wave & 1;
  const int fr = lane & 15, kb = lane >> 4;
  const int bm = blockIdx.y, bn = blockIdx.x;

  // staging: thread t covers LDS bytes [t*16, t*16+16) (+4096 for 2nd issue)
  const int sr = tid >> 2;            // row 0..63
  const int sc = (tid & 3) * 8;       // half-offset within BK=32
  const __half* gA = A  + (size_t)(bm * 128 + sr) * K + sc;
  const __half* gB = Bt + (size_t)(bn * 128 + sr) * K + sc;
  __half* lA = As + tid * 8;
  __half* lB = Bs + tid * 8;

  f32x4_t acc[4][4] = {};

  const int nk = K >> 5;
  for (int kt = 0; kt < nk; ++kt) {
    const __half* ga = gA + (size_t)kt * 32;
    const __half* gb = gB + (size_t)kt * 32;
    gload_lds16(ga, lA);
    gload_lds16(ga + (size_t)64 * K, lA + 2048);
    gload_lds16(gb, lB);
    gload_lds16(gb + (size_t)64 * K, lB + 2048);
    __syncthreads();
    half8_t af[4], bf[4];
#pragma unroll
    for (int m = 0; m < 4; ++m)
      af[m] = *(const half8_t*)(As + (wr * 64 + m * 16 + fr) * 32 + kb * 8);
#pragma unroll
    for (int n = 0; n < 4; ++n)
      bf[n] = *(const half8_t*)(Bs + (wc * 64 + n * 16 + fr) * 32 + kb * 8);
#pragma unroll
    for (int m = 0; m < 4; ++m)
#pragma unroll
      for (int n = 0; n < 4; ++n)
        acc[m][n] = __builtin_amdgcn_mfma_f32_16x16x32_f16(af[m], bf[n], acc[m][n], 0, 0, 0);
    __syncthreads();
  }

  float gate = 0.f;
  if (MODE == 3) gate = tanhf(gate_p[0]);

#pragma unroll
  for (int m = 0; m < 4; ++m) {
#pragma unroll
    for (int n = 0; n < 4; ++n) {
#pragma unroll
      for (int r = 0; r < 4; ++r) {
        const int row = bm * 128 + wr * 64 + m * 16 + kb * 4 + r;
        const int col = bn * 128 + wc * 64 + n * 16 + fr;
        const float v = acc[m][n][r];
        if (MODE == 0) {
          const int b = row >> 11, s = row & 2047;
          const int h = col / DHD, d = col - h * DHD;
          ((__half*)Cout)[(((size_t)(b * NH + h)) * NS + s) * DHP + d] =
              __float2half(v * 0.11180339887498949f);  // 1/sqrt(80) folded into Q
        } else if (MODE == 1) {
          const int b = row >> 9, l = row & 511;
          const int h = col / DHD, d = col - h * DHD;
          ((__half*)Cout)[(((size_t)(b * NH + h)) * NL + l) * DHP + d] = __float2half(v);
        } else if (MODE == 2) {
          const int b = row >> 9, l = row & 511;
          const int h = col / DHD, d = col - h * DHD;
          ((__half*)Cout)[(((size_t)(b * NH + h)) * DHP + d) * NL + l] = __float2half(v);
        } else {
          ((float*)Cout)[(size_t)row * HID + col] = gate * v;
        }
      }
    }
  }
}

// ---------------- attention: scores -> exact softmax -> P out + PV -------
// grid (NS/64, NB*NH); 4 waves x 16 Q-rows each. L=512 scores per row in
// registers (32 f32x4/lane). Softmax reduced across 16-lane col groups.
__global__ __launch_bounds__(256) void attn_kernel(const __half* __restrict__ Q,
                                                   const __half* __restrict__ Kt,
                                                   const __half* __restrict__ Vt,
                                                   float* __restrict__ P,
                                                   __half* __restrict__ AO) {
  // per-wave P tile 16x512 fp16, row stride 520 halfs (1040 B: 16B-aligned,
  // 2-way bank aliasing only = free)
  __shared__ __half Pl[4 * 16 * 520];
  const int tid = threadIdx.x;
  const int lane = tid & 63, wave = tid >> 6;
  const int fr = lane & 15, kb = lane >> 4;
  const int bh = blockIdx.y;
  const int r0 = blockIdx.x * 64 + wave * 16;

  const __half* Qb = Q  + ((size_t)bh * NS + r0) * DHP;
  const __half* Kb = Kt + (size_t)bh * NL * DHP;
  const __half* Vb = Vt + (size_t)bh * DHP * NL;

  // Q A-fragments (rows r0..r0+15, K = 96 padded, pad zeros)
  half8_t aq[3];
#pragma unroll
  for (int kk = 0; kk < 3; ++kk)
    aq[kk] = *(const half8_t*)(Qb + (size_t)fr * DHP + kk * 32 + kb * 8);

  // scores: 32 col-tiles of 16
  f32x4_t scr[32];
#pragma unroll
  for (int nt = 0; nt < 32; ++nt) {
    f32x4_t a = {};
#pragma unroll
    for (int kk = 0; kk < 3; ++kk) {
      half8_t bf = *(const half8_t*)(Kb + (size_t)(nt * 16 + fr) * DHP + kk * 32 + kb * 8);
      a = __builtin_amdgcn_mfma_f32_16x16x32_f16(aq[kk], bf, a, 0, 0, 0);
    }
    scr[nt] = a;
  }

  // softmax: lane holds rows kb*4+r (r=0..3), col nt*16+fr
  __half* Plw = Pl + wave * (16 * 520);
#pragma unroll
  for (int r = 0; r < 4; ++r) {
    float m = -1e30f;
#pragma unroll
    for (int nt = 0; nt < 32; ++nt) m = fmaxf(m, scr[nt][r]);
#pragma unroll
    for (int d = 1; d < 16; d <<= 1) m = fmaxf(m, __shfl_xor(m, d));
    float s = 0.f;
#pragma unroll
    for (int nt = 0; nt < 32; ++nt) {
      float p = __expf(scr[nt][r] - m);
      scr[nt][r] = p;
      s += p;
    }
#pragma unroll
    for (int d = 1; d < 16; d <<= 1) s += __shfl_xor(s, d);
    const float iv = 1.f / s;
    const int srow = r0 + kb * 4 + r;
    float* Pr = P + ((size_t)bh * NS + srow) * NL;
#pragma unroll
    for (int nt = 0; nt < 32; ++nt) {
      float p = scr[nt][r] * iv;
      Pr[nt * 16 + fr] = p;                                  // exact attn_weights
      Plw[(kb * 4 + r) * 520 + nt * 16 + fr] = __float2half(p);
    }
  }
  __syncthreads();

  // PV: out[16 x 80], A = P from LDS, B = V^T frags from global (L2-resident)
  f32x4_t oc[5] = {};
#pragma unroll
  for (int k0 = 0; k0 < 16; ++k0) {
    half8_t ap = *(const half8_t*)(Plw + fr * 520 + k0 * 32 + kb * 8);
#pragma unroll
    for (int n = 0; n < 5; ++n) {
      half8_t bv = *(const half8_t*)(Vb + (size_t)(n * 16 + fr) * NL + k0 * 32 + kb * 8);
      oc[n] = __builtin_amdgcn_mfma_f32_16x16x32_f16(ap, bv, oc[n], 0, 0, 0);
    }
  }

  const int b = bh >> 5, h = bh & 31;
#pragma unroll
  for (int n = 0; n < 5; ++n)
#pragma unroll
    for (int r = 0; r < 4; ++r) {
      const int srow = r0 + kb * 4 + r;
      AO[((size_t)b * NS + srow) * HID + h * DHD + n * 16 + fr] = __float2half(oc[n][r]);
    }
}

extern "C" void kernel_launch(void* const* d_in, const int* in_sizes, int n_in,
                              void* d_out, int out_size, void* d_ws, size_t ws_size,
                              hipStream_t stream) {
  const float* X  = (const float*)d_in[0];
  const float* LS = (const float*)d_in[1];
  const float* Wq = (const float*)d_in[2];
  const float* Wk = (const float*)d_in[3];
  const float* Wv = (const float*)d_in[4];
  const float* Wo = (const float*)d_in[5];
  const float* gp = (const float*)d_in[6];
  float* out  = (float*)d_out;
  float* Pout = out + (size_t)NB * NS * HID;  // attn_weights, output index 1

  char* w = (char*)d_ws;
  auto alloc = [&](size_t bytes) {
    char* p = w;
    w += (bytes + 255) & ~(size_t)255;
    return p;
  };
  __half* Xh  = (__half*)alloc((size_t)NB * NS * HID * 2);
  __half* Lh  = (__half*)alloc((size_t)NB * NL * HID * 2);
  __half* Wqh = (__half*)alloc((size_t)HID * HID * 2);
  __half* Wkh = (__half*)alloc((size_t)HID * HID * 2);
  __half* Wvh = (__half*)alloc((size_t)HID * HID * 2);
  __half* Woh = (__half*)alloc((size_t)HID * HID * 2);
  __half* Qa  = (__half*)alloc((size_t)NB * NH * NS * DHP * 2);
  __half* Ka  = (__half*)alloc((size_t)NB * NH * NL * DHP * 2);
  __half* Va  = (__half*)alloc((size_t)NB * NH * DHP * NL * 2);
  __half* AOh = Xh;  // alias: Xh is dead after the Q projection

  auto cast = [&](const float* src, __half* dst, size_t n) {
    int n4 = (int)(n / 4);
    cast_f2h<<<dim3((n4 + 255) / 256), dim3(256), 0, stream>>>(src, dst, n4);
  };
  cast(X,  Xh,  (size_t)NB * NS * HID);
  cast(LS, Lh,  (size_t)NB * NL * HID);
  cast(Wq, Wqh, (size_t)HID * HID);
  cast(Wk, Wkh, (size_t)HID * HID);
  cast(Wv, Wvh, (size_t)HID * HID);
  cast(Wo, Woh, (size_t)HID * HID);

  // zero the DHP pads of Q/K (their pad columns enter the K=96 MFMA loop)
  hipMemsetAsync(Qa, 0, (size_t)NB * NH * NS * DHP * 2, stream);
  hipMemsetAsync(Ka, 0, (size_t)NB * NH * NL * DHP * 2, stream);

  gemm_bt<0><<<dim3(HID / 128, NB * NS / 128), dim3(256), 0, stream>>>(
      Xh, Wqh, Qa, NB * NS, HID, HID, nullptr);
  gemm_bt<1><<<dim3(HID / 128, NB * NL / 128), dim3(256), 0, stream>>>(
      Lh, Wkh, Ka, NB * NL, HID, HID, nullptr);
  gemm_bt<2><<<dim3(HID / 128, NB * NL / 128), dim3(256), 0, stream>>>(
      Lh, Wvh, Va, NB * NL, HID, HID, nullptr);
  attn_kernel<<<dim3(NS / 64, NB * NH), dim3(256), 0, stream>>>(
      Qa, Ka, Va, Pout, AOh);
  gemm_bt<3><<<dim3(HID / 128, NB * NS / 128), dim3(256), 0, stream>>>(
      AOh, Woh, out, NB * NS, HID, HID, gp);
}